// Round 3
// baseline (330.760 us; speedup 1.0000x reference)
//
#include <hip/hip_runtime.h>

// norm_conv: im2col(3x3 reflect) -> row-normalize -> GEMM[576x64], fused.
// R3: HBM duty-cycle attack. R1/R2 serialized stage->MFMA->store phases
// (HBM ~50% idle). Now: 256 persistent blocks (1/CU), 512 thr, each owns one
// image, loops 4 quarter-tiles with double-buffered LDS. Next tile's global
// loads (40 dwords/thread -> regs) issue BEFORE the MFMA phase; convert+LDS
// write after. B-frags (144 regs, f=1/2) in regs; __launch_bounds__(512,2).
//   out = (patches@W - mean*colsum(W)) * inv_std   (norm folded into epilogue)

#define STRIDE 68            // ushorts per pixel in LDS (136 B = 34 banks; 0 conflicts measured R1/R2)
#define NPIX   320           // 10 rows x 32 cols staged per quarter

typedef __attribute__((ext_vector_type(8))) short bf16x8;
typedef __attribute__((ext_vector_type(4))) short bf16x4;
typedef __attribute__((ext_vector_type(4))) float f32x4;

__device__ __forceinline__ unsigned short f2bf(float f) {
    union { float f; unsigned u; } v; v.f = f;
    unsigned r = v.u + 0x7FFFu + ((v.u >> 16) & 1u);   // RNE
    return (unsigned short)(r >> 16);
}

__device__ __forceinline__ float bf2f(unsigned short h) {
    union { unsigned u; float f; } v; v.u = ((unsigned)h) << 16;
    return v.f;
}

__device__ __forceinline__ int reflect32(int x) {      // jnp.pad 'reflect', pad=1
    x = (x < 0) ? -x : x;
    return (x > 31) ? (62 - x) : x;
}

// blocks 0..17: pack W (fp32->bf16) into per-lane B-frag layout wf[4][18][64].
// block 18: scol[o] = sum_k bf16(W[k][o]).
// B[k'][o]: o = ntg*16 + (lane&15), k' = ks*32 + (lane>>4)*8 + j,
// reordered k' = (kh*3+kw)*64 + c  <->  reference k = c*9 + (kh*3+kw).
__global__ void prep_kernel(const float* __restrict__ W, uint4* __restrict__ wf,
                            float* __restrict__ scolg) {
    if (blockIdx.x == 18) {
        __shared__ float red[256];
        int t = threadIdx.x;
        int o = t & 63, kq = t >> 6;
        float s = 0.f;
        for (int k = kq * 144; k < kq * 144 + 144; ++k)
            s += bf2f(f2bf(W[k * 64 + o]));
        red[t] = s;
        __syncthreads();
        if (t < 64) scolg[t] = red[t] + red[t + 64] + red[t + 128] + red[t + 192];
        return;
    }
    int idx = blockIdx.x * 256 + threadIdx.x;   // 0..4607
    int lane = idx & 63;
    int ks   = (idx >> 6) % 18;
    int ntg  = idx / 1152;
    int quad = lane >> 4;
    int o    = ntg * 16 + (lane & 15);
    unsigned short v[8];
    #pragma unroll
    for (int j = 0; j < 8; ++j) {
        int kp = ks * 32 + quad * 8 + j;
        int c  = kp & 63;
        int s  = kp >> 6;
        v[j] = f2bf(W[(c * 9 + s) * 64 + o]);
    }
    uint4 r;
    r.x = (unsigned)v[0] | ((unsigned)v[1] << 16);
    r.y = (unsigned)v[2] | ((unsigned)v[3] << 16);
    r.z = (unsigned)v[4] | ((unsigned)v[5] << 16);
    r.w = (unsigned)v[6] | ((unsigned)v[7] << 16);
    wf[idx] = r;
}

// staged row bases per quarter (10 rows cover out rows [8q,8q+8) + reflect halo)
__device__ __constant__ int c_rb[4] = {0, 7, 15, 22};

// Issue the 40 global loads for quarter qq (no waiting; results land in vals).
__device__ __forceinline__ void stage_issue(const float* __restrict__ Ab,
                                            int tid, float* vals) {
    #pragma unroll
    for (int k = 0; k < 10; ++k) {
        int u  = tid + 512 * k;          // 5120 units = 320 px x 16 c4-groups
        int c4 = u / 320;
        int p  = u - c4 * 320;
        #pragma unroll
        for (int j = 0; j < 4; ++j)
            vals[k * 4 + j] = Ab[(c4 * 4 + j) * 1024 + p];   // lanes: consecutive p -> coalesced
    }
}

// Convert vals -> bf16 and write into the LDS image buffer (ds_write_b64).
__device__ __forceinline__ void stage_commit(unsigned short* __restrict__ imgb,
                                             int tid, const float* vals) {
    #pragma unroll
    for (int k = 0; k < 10; ++k) {
        int u  = tid + 512 * k;
        int c4 = u / 320;
        int p  = u - c4 * 320;
        uint2 pk;
        pk.x = (unsigned)f2bf(vals[k * 4 + 0]) | ((unsigned)f2bf(vals[k * 4 + 1]) << 16);
        pk.y = (unsigned)f2bf(vals[k * 4 + 2]) | ((unsigned)f2bf(vals[k * 4 + 3]) << 16);
        *(uint2*)&imgb[p * STRIDE + c4 * 4] = pk;   // 8B-aligned, 2-way banks (free)
    }
}

__global__ __launch_bounds__(512, 2)
void norm_conv_kernel(const float* __restrict__ a,
                      const uint4* __restrict__ wf,
                      const float* __restrict__ scolg,
                      float* __restrict__ out) {
    __shared__ unsigned short img[2][NPIX * STRIDE];   // 2 x 43,520 B
    __shared__ float sums[2 * NPIX];                   // csum | cssq (transient)
    __shared__ float stats[2][512];                    // (mean,inv) pairs per buf

    const int tid  = threadIdx.x;
    const int b    = blockIdx.x;                       // one image per block
    const int lane = tid & 63;
    const int wid  = tid >> 6;                         // 8 waves
    const int ng   = wid & 1;                          // n-half: o in [ng*32, +32)
    const int wq   = wid >> 1;                         // m-quarter: 4 mt each
    const int quad = lane >> 4;
    const int mlan = lane & 15;

    // ---- B fragments: 2 n-tiles x 18 k-steps in registers (144 VGPR/AGPR) ----
    bf16x8 bfrag[2][18];
    #pragma unroll
    for (int nt = 0; nt < 2; ++nt)
        #pragma unroll
        for (int ks = 0; ks < 18; ++ks) {
            union { uint4 u; bf16x8 v; } cvt;
            cvt.u = wf[((ng * 2 + nt) * 18 + ks) * 64 + lane];
            bfrag[nt][ks] = cvt.v;
        }
    float So[2];
    So[0] = scolg[(ng * 2 + 0) * 16 + mlan];
    So[1] = scolg[(ng * 2 + 1) * 16 + mlan];

    const float* Aimg = a + (size_t)b * 65536;
    float* outB = out + (size_t)b * 65536;

    // ---- prologue: stage quarter 0 into buf 0 ----
    {
        float vals[40];
        stage_issue(Aimg + c_rb[0] * 32, tid, vals);
        stage_commit(img[0], tid, vals);
        __syncthreads();
        if (tid < NPIX) {                      // per-pixel channel sums from bf16 image
            float s = 0.f, ss = 0.f;
            const unsigned short* row = &img[0][tid * STRIDE];
            #pragma unroll
            for (int g = 0; g < 16; ++g) {
                uint2 w4 = *(const uint2*)&row[g * 4];
                float f0 = bf2f((unsigned short)(w4.x & 0xFFFF));
                float f1 = bf2f((unsigned short)(w4.x >> 16));
                float f2 = bf2f((unsigned short)(w4.y & 0xFFFF));
                float f3 = bf2f((unsigned short)(w4.y >> 16));
                s  += (f0 + f1) + (f2 + f3);
                ss += (f0 * f0 + f1 * f1) + (f2 * f2 + f3 * f3);
            }
            sums[tid] = s; sums[NPIX + tid] = ss;
        }
        __syncthreads();
        if (tid < 256) {                       // 3x3 box -> mean, inv_std
            int hg = (tid >> 5);               // quarter 0
            int wg = tid & 31;
            float s = 0.f, ss = 0.f;
            #pragma unroll
            for (int kh = 0; kh < 3; ++kh) {
                int hr = reflect32(hg + kh - 1) - c_rb[0];
                #pragma unroll
                for (int kw = 0; kw < 3; ++kw) {
                    int p = hr * 32 + reflect32(wg + kw - 1);
                    s  += sums[p];
                    ss += sums[NPIX + p];
                }
            }
            float mean = s * (1.0f / 576.0f);
            stats[0][tid * 2]     = mean;
            stats[0][tid * 2 + 1] = rsqrtf((ss - s * mean) * (1.0f / 575.0f));
        }
        __syncthreads();
    }

    // ---- main loop over quarters, software-pipelined ----
    for (int q = 0; q < 4; ++q) {
        const int cur = q & 1, nxt = cur ^ 1;
        float vals[40];
        if (q < 3)                                        // phase A: issue loads for q+1
            stage_issue(Aimg + c_rb[q + 1] * 32, tid, vals);

        // phase B: MFMA on quarter q (buf cur) while loads are in flight
        const unsigned short* imgb = img[cur];
        const char* imgc = (const char*)imgb;
        const float* st  = stats[cur];
        const int rb = c_rb[q];
        for (int i = 0; i < 4; ++i) {
            int mt = wq * 4 + i;
            int hg = q * 8 + (mt >> 1);
            int wl = ((mt & 1) << 4) + mlan;
            int base9[9];
            #pragma unroll
            for (int kh = 0; kh < 3; ++kh) {
                int pr = (reflect32(hg + kh - 1) - rb) * 32;
                #pragma unroll
                for (int kw = 0; kw < 3; ++kw)
                    base9[kh * 3 + kw] = ((pr + reflect32(wl + kw - 1)) * STRIDE + quad * 8) * 2;
            }
            f32x4 acc0 = {0.f, 0.f, 0.f, 0.f};
            f32x4 acc1 = {0.f, 0.f, 0.f, 0.f};
            #pragma unroll
            for (int ks = 0; ks < 18; ++ks) {
                int off = base9[ks >> 1] + (ks & 1) * 64;
                bf16x4 flo = *(const bf16x4*)(imgc + off);       // ds_read_b64 x2
                bf16x4 fhi = *(const bf16x4*)(imgc + off + 8);
                bf16x8 af  = __builtin_shufflevector(flo, fhi, 0, 1, 2, 3, 4, 5, 6, 7);
                acc0 = __builtin_amdgcn_mfma_f32_16x16x32_bf16(af, bfrag[0][ks], acc0, 0, 0, 0);
                acc1 = __builtin_amdgcn_mfma_f32_16x16x32_bf16(af, bfrag[1][ks], acc1, 0, 0, 0);
            }
            int l0 = mt * 16 + quad * 4;                         // local px in quarter
            f32x4 r0, r1;
            #pragma unroll
            for (int r = 0; r < 4; ++r) {
                float mean = st[(l0 + r) * 2];
                float inv  = st[(l0 + r) * 2 + 1];
                r0[r] = (acc0[r] - mean * So[0]) * inv;
                r1[r] = (acc1[r] - mean * So[1]) * inv;
            }
            int o0 = (ng * 2) * 16 + mlan;
            *(f32x4*)(outB + o0 * 1024 + q * 256 + l0) = r0;
            *(f32x4*)(outB + (o0 + 16) * 1024 + q * 256 + l0) = r1;
        }

        if (q < 3) {
            // phase C: commit staged tile q+1 to the other LDS buffer
            stage_commit(img[nxt], tid, vals);
            __syncthreads();
            // phase D1: per-pixel channel sums from bf16 image
            if (tid < NPIX) {
                float s = 0.f, ss = 0.f;
                const unsigned short* row = &img[nxt][tid * STRIDE];
                #pragma unroll
                for (int g = 0; g < 16; ++g) {
                    uint2 w4 = *(const uint2*)&row[g * 4];
                    float f0 = bf2f((unsigned short)(w4.x & 0xFFFF));
                    float f1 = bf2f((unsigned short)(w4.x >> 16));
                    float f2 = bf2f((unsigned short)(w4.y & 0xFFFF));
                    float f3 = bf2f((unsigned short)(w4.y >> 16));
                    s  += (f0 + f1) + (f2 + f3);
                    ss += (f0 * f0 + f1 * f1) + (f2 * f2 + f3 * f3);
                }
                sums[tid] = s; sums[NPIX + tid] = ss;
            }
            __syncthreads();
            // phase D2: stats for quarter q+1
            if (tid < 256) {
                int hg = (q + 1) * 8 + (tid >> 5);
                int wg = tid & 31;
                float s = 0.f, ss = 0.f;
                #pragma unroll
                for (int kh = 0; kh < 3; ++kh) {
                    int hr = reflect32(hg + kh - 1) - c_rb[q + 1];
                    #pragma unroll
                    for (int kw = 0; kw < 3; ++kw) {
                        int p = hr * 32 + reflect32(wg + kw - 1);
                        s  += sums[p];
                        ss += sums[NPIX + p];
                    }
                }
                float mean = s * (1.0f / 576.0f);
                stats[nxt][tid * 2]     = mean;
                stats[nxt][tid * 2 + 1] = rsqrtf((ss - s * mean) * (1.0f / 575.0f));
            }
            __syncthreads();
        }
    }
}

extern "C" void kernel_launch(void* const* d_in, const int* in_sizes, int n_in,
                              void* d_out, int out_size, void* d_ws, size_t ws_size,
                              hipStream_t stream) {
    const float* a = (const float*)d_in[0];
    const float* w = (const float*)d_in[1];
    float* out = (float*)d_out;
    uint4* wf = (uint4*)d_ws;                                  // 73,728 B
    float* scolg = (float*)((char*)d_ws + 73728);              // 256 B
    prep_kernel<<<dim3(19), dim3(256), 0, stream>>>(w, wf, scolg);
    norm_conv_kernel<<<dim3(256), dim3(512), 0, stream>>>(a, wf, scolg, out);
}

// Round 4
// 142.508 us; speedup vs baseline: 2.3210x; 2.3210x over previous
//
#include <hip/hip_runtime.h>

// norm_conv: im2col(3x3 reflect) -> row-normalize -> GEMM[576x64], fused.
// R4: producer/consumer wave specialization. R3 spilled (vals[40]+144 B-frags
// in one wave's 256-reg budget -> 500 MB scratch traffic). Now: waves 0-3 =
// consumers (B-frags in regs, 32x32x16 MFMA), waves 4-7 = producers (global->
// LDS staging + channel sums). Divergent paths -> reg alloc = max, not sum.
// Double-buffered quarter-image LDS, 1 barrier per quarter, 256 blocks
// (1/CU, 1 image each).  out = (patches@W - mean*colsum(W)) * inv_std.

#define STRIDE 68            // ushorts per pixel in LDS (136 B; 0 conflicts measured R1/R2)
#define NPIX   320           // 10 rows x 32 cols staged per quarter

typedef __attribute__((ext_vector_type(8))) short bf16x8;
typedef __attribute__((ext_vector_type(4))) short bf16x4;
typedef __attribute__((ext_vector_type(4))) float f32x4;
typedef __attribute__((ext_vector_type(16))) float f32x16;

__device__ __forceinline__ unsigned short f2bf(float f) {
    union { float f; unsigned u; } v; v.f = f;
    unsigned r = v.u + 0x7FFFu + ((v.u >> 16) & 1u);   // RNE
    return (unsigned short)(r >> 16);
}
__device__ __forceinline__ float bf2f(unsigned short h) {
    union { unsigned u; float f; } v; v.u = ((unsigned)h) << 16;
    return v.f;
}
__device__ __forceinline__ int reflect32(int x) {      // jnp.pad 'reflect', pad=1
    x = (x < 0) ? -x : x;
    return (x > 31) ? (62 - x) : x;
}

__device__ __constant__ int c_rb[4] = {0, 7, 15, 22}; // staged row base per quarter

// blocks 0..17: pack W (fp32->bf16) into 32x32x16 B-frag layout wf[2][36][64].
// B[k'][o]: o = ntg*32 + (lane&31), k' = ks*16 + (lane>>5)*8 + j,
// reordered k' = (kh*3+kw)*64 + c  <->  reference k = c*9 + (kh*3+kw).
// block 18: scol[o] = sum_k bf16(W[k][o]).
__global__ void prep_kernel(const float* __restrict__ W, uint4* __restrict__ wf,
                            float* __restrict__ scolg) {
    if (blockIdx.x == 18) {
        __shared__ float red[256];
        int t = threadIdx.x;
        int o = t & 63, kq = t >> 6;
        float s = 0.f;
        for (int k = kq * 144; k < kq * 144 + 144; ++k)
            s += bf2f(f2bf(W[k * 64 + o]));
        red[t] = s;
        __syncthreads();
        if (t < 64) scolg[t] = red[t] + red[t + 64] + red[t + 128] + red[t + 192];
        return;
    }
    int idx = blockIdx.x * 256 + threadIdx.x;   // 0..4607
    int lane = idx & 63;
    int ks   = (idx >> 6) % 36;
    int ntg  = idx / 2304;                      // 36*64
    int o    = ntg * 32 + (lane & 31);
    int kb   = ks * 16 + (lane >> 5) * 8;
    unsigned short v[8];
    #pragma unroll
    for (int j = 0; j < 8; ++j) {
        int kp = kb + j;
        int c  = kp & 63;
        int s  = kp >> 6;
        v[j] = f2bf(W[(c * 9 + s) * 64 + o]);
    }
    uint4 r;
    r.x = (unsigned)v[0] | ((unsigned)v[1] << 16);
    r.y = (unsigned)v[2] | ((unsigned)v[3] << 16);
    r.z = (unsigned)v[4] | ((unsigned)v[5] << 16);
    r.w = (unsigned)v[6] | ((unsigned)v[7] << 16);
    wf[idx] = r;
}

// Producer: stage one quarter (10 rows) fp32->bf16 into LDS + per-(pixel,
// 16ch-group) partial sums. 1280 units = 4 cgroups x 320 px over 256 threads.
__device__ __forceinline__ void stage_quarter(const float* __restrict__ Ab, int ptid,
                                              unsigned short* __restrict__ imgb,
                                              float* __restrict__ sums4b) {
    #pragma unroll
    for (int k = 0; k < 5; ++k) {
        int u  = k * 256 + ptid;
        int cg = u / 320;
        int p  = u - cg * 320;
        float v[16];
        #pragma unroll
        for (int j = 0; j < 16; ++j)
            v[j] = Ab[(cg * 16 + j) * 1024 + p];   // lanes: consecutive p -> coalesced
        float s = 0.f, ss = 0.f;
        unsigned pk[8];
        #pragma unroll
        for (int j = 0; j < 8; ++j) {
            float v0 = v[2 * j], v1 = v[2 * j + 1];
            s  += v0 + v1;
            ss += v0 * v0 + v1 * v1;
            pk[j] = (unsigned)f2bf(v0) | ((unsigned)f2bf(v1) << 16);
        }
        unsigned short* row = &imgb[p * STRIDE + cg * 16];
        #pragma unroll
        for (int j = 0; j < 4; ++j) {
            uint2 t; t.x = pk[2 * j]; t.y = pk[2 * j + 1];
            *(uint2*)&row[j * 4] = t;              // ds_write_b64, 8B-aligned
        }
        float2 sv; sv.x = s; sv.y = ss;
        *(float2*)&sums4b[cg * (NPIX * 2) + p * 2] = sv;
    }
}

__global__ __launch_bounds__(512, 2)
void norm_conv_kernel(const float* __restrict__ a,
                      const uint4* __restrict__ wf,
                      const float* __restrict__ scolg,
                      float* __restrict__ out) {
    __shared__ unsigned short img[2][NPIX * STRIDE];   // 2 x 43,520 B
    __shared__ float sums4[2][4 * NPIX * 2];           // 2 x 10,240 B (s,ss per cg,px)
    __shared__ float stats_s[4][256];                  // per consumer wave: 128 px x (mean,inv)

    const int tid  = threadIdx.x;
    const int lane = tid & 63;
    const int wid  = tid >> 6;
    const float* Aimg = a + (size_t)blockIdx.x * 65536;
    float* outB = out + (size_t)blockIdx.x * 65536;

    if (wid >= 4) {
        // ================= producers (waves 4-7) =================
        const int ptid = tid - 256;
        stage_quarter(Aimg + c_rb[0] * 32, ptid, img[0], sums4[0]);   // prologue: q0
        __syncthreads();
        for (int q = 0; q < 4; ++q) {
            if (q < 3)
                stage_quarter(Aimg + c_rb[q + 1] * 32, ptid,
                              img[(q + 1) & 1], sums4[(q + 1) & 1]);
            __syncthreads();
        }
    } else {
        // ================= consumers (waves 0-3) =================
        const int nt = wid & 1;            // n-half: o in [nt*32, +32)
        const int mq = wid >> 1;           // m-half: rows [q*8+mq*4, +4) per quarter
        const int nl = lane & 31;
        const int hq = lane >> 5;

        bf16x8 bfrag[36];                  // 144 regs: this wave's n-half of W
        #pragma unroll
        for (int ks = 0; ks < 36; ++ks) {
            union { uint4 u; bf16x8 v; } cvt;
            cvt.u = wf[(nt * 36 + ks) * 64 + lane];
            bfrag[ks] = cvt.v;
        }
        const float So = scolg[nt * 32 + nl];
        __syncthreads();

        for (int q = 0; q < 4; ++q) {
            const int cur = q & 1;
            const int rb = c_rb[q];
            const float* s4 = sums4[cur];

            // ---- stats for this wave's 128 px (2 per lane) ----
            float st4[4];
            #pragma unroll
            for (int e = 0; e < 2; ++e) {
                int lq = mq * 128 + lane * 2 + e;     // quarter-local px
                int hg = q * 8 + (lq >> 5);
                int wg = lq & 31;
                float s = 0.f, ss = 0.f;
                #pragma unroll
                for (int kh = 0; kh < 3; ++kh) {
                    int hr = reflect32(hg + kh - 1) - rb;
                    #pragma unroll
                    for (int kw = 0; kw < 3; ++kw) {
                        int p = hr * 32 + reflect32(wg + kw - 1);
                        #pragma unroll
                        for (int cg = 0; cg < 4; ++cg) {
                            float2 sv = *(const float2*)&s4[cg * (NPIX * 2) + p * 2];
                            s += sv.x; ss += sv.y;
                        }
                    }
                }
                float mean = s * (1.0f / 576.0f);
                st4[e * 2]     = mean;
                st4[e * 2 + 1] = rsqrtf((ss - s * mean) * (1.0f / 575.0f));
            }
            f32x4 stw; stw[0] = st4[0]; stw[1] = st4[1]; stw[2] = st4[2]; stw[3] = st4[3];
            *(f32x4*)&stats_s[wid][lane * 4] = stw;
            __builtin_amdgcn_s_waitcnt(0);            // LDS write visible within wave

            // ---- 4 m-tiles (one image row of 32 px each), K=576 = 36 k-steps ----
            const char* imgc = (const char*)img[cur];
            for (int i = 0; i < 4; ++i) {
                const int mt = mq * 4 + i;
                const int hg = q * 8 + mt;
                int base9[9];
                #pragma unroll
                for (int kh = 0; kh < 3; ++kh) {
                    int hr = reflect32(hg + kh - 1) - rb;
                    #pragma unroll
                    for (int kw = 0; kw < 3; ++kw)
                        base9[kh * 3 + kw] =
                            ((hr * 32 + reflect32(nl + kw - 1)) * STRIDE + hq * 8) * 2;
                }
                f32x16 acc = {0.f,0.f,0.f,0.f,0.f,0.f,0.f,0.f,
                              0.f,0.f,0.f,0.f,0.f,0.f,0.f,0.f};
                #pragma unroll
                for (int ks = 0; ks < 36; ++ks) {
                    int off = base9[ks >> 2] + (ks & 3) * 32;
                    bf16x4 flo = *(const bf16x4*)(imgc + off);     // ds_read_b64 x2
                    bf16x4 fhi = *(const bf16x4*)(imgc + off + 8);
                    bf16x8 af  = __builtin_shufflevector(flo, fhi, 0, 1, 2, 3, 4, 5, 6, 7);
                    acc = __builtin_amdgcn_mfma_f32_32x32x16_bf16(af, bfrag[ks], acc, 0, 0, 0);
                }
                // D: col(o-within-nt) = lane&31, row(px-col m) = (reg&3)+8*(reg>>2)+4*hq
                float* op = outB + (nt * 32 + nl) * 1024 + hg * 32;
                #pragma unroll
                for (int g = 0; g < 4; ++g) {
                    int m0 = g * 8 + hq * 4;                       // 4 consecutive px
                    f32x4 st0 = *(const f32x4*)&stats_s[wid][(i * 32 + m0) * 2];
                    f32x4 st1 = *(const f32x4*)&stats_s[wid][(i * 32 + m0) * 2 + 4];
                    f32x4 rr;
                    rr[0] = (acc[g * 4 + 0] - st0[0] * So) * st0[1];
                    rr[1] = (acc[g * 4 + 1] - st0[2] * So) * st0[3];
                    rr[2] = (acc[g * 4 + 2] - st1[0] * So) * st1[1];
                    rr[3] = (acc[g * 4 + 3] - st1[2] * So) * st1[3];
                    *(f32x4*)(op + m0) = rr;
                }
            }
            __syncthreads();
        }
    }
}

extern "C" void kernel_launch(void* const* d_in, const int* in_sizes, int n_in,
                              void* d_out, int out_size, void* d_ws, size_t ws_size,
                              hipStream_t stream) {
    const float* a = (const float*)d_in[0];
    const float* w = (const float*)d_in[1];
    float* out = (float*)d_out;
    uint4* wf = (uint4*)d_ws;                                  // 73,728 B
    float* scolg = (float*)((char*)d_ws + 73728);              // 256 B
    prep_kernel<<<dim3(19), dim3(256), 0, stream>>>(w, wf, scolg);
    norm_conv_kernel<<<dim3(256), dim3(512), 0, stream>>>(a, wf, scolg, out);
}